// Round 10
// baseline (569.965 us; speedup 1.0000x reference)
//
#include <hip/hip_runtime.h>
#include <hip/hip_bf16.h>
#include <math.h>

// Problem constants
#define Bn   32
#define Hh   56
#define Wd   56
#define Cc   192
#define NHh  6
#define HDim 32
#define HIDN 768
#define Tt   (Bn*Hh*Wd)          // 100352 tokens
#define NWIN (Bn*64)             // 2048 windows

typedef __attribute__((ext_vector_type(8))) short short8;
typedef __attribute__((ext_vector_type(4))) short s4v;
typedef __attribute__((ext_vector_type(4))) float floatx4;

__device__ __forceinline__ short f2bf(float f) {
    unsigned u = __float_as_uint(f);
    u += 0x7fffu + ((u >> 16) & 1u);     // round-to-nearest-even
    return (short)(u >> 16);
}
__device__ __forceinline__ float bf2f(short s) {
    return __uint_as_float(((unsigned)(unsigned short)s) << 16);
}

// async global->LDS, 16B per lane. LDS dest is wave-uniform base + lane*16;
// caller must pass a lane-linear LDS pointer (ptr = base + lane*8 shorts).
__device__ __forceinline__ void gl_lds16(const short* g, short* l) {
    __builtin_amdgcn_global_load_lds(
        (const __attribute__((address_space(1))) unsigned int*)g,
        (__attribute__((address_space(3))) unsigned int*)l,
        16, 0, 0);
}

// XCD-aware bijective block swizzle (requires nb % 8 == 0): each XCD gets a
// contiguous chunk of the flat block range -> neighbor blocks share an L2.
__device__ __forceinline__ int xcd_swz(int bid, int nb) {
    return (bid & 7) * (nb >> 3) + (bid >> 3);
}

// ---------------------------------------------------------------------------
// Weight transpose + bf16 convert: W[K,N] fp32 -> WT[N,K] bf16
// ---------------------------------------------------------------------------
__global__ void k_transpose(const float* __restrict__ W, short* __restrict__ WT,
                            int K, int N) {
    int idx = blockIdx.x * 256 + threadIdx.x;
    if (idx >= K * N) return;
    int n = idx / K, k = idx % K;        // coalesced writes
    WT[idx] = f2bf(W[k * N + n]);
}

// ---------------------------------------------------------------------------
// QKV weight transpose with COLUMN PERMUTATION:
// reference column order is (d k h): col = d*18 + k*6 + h.
// We emit new order col' = k*192 + h*32 + d so the GEMM writes qkvbuf in a
// per-(k,head) contiguous-d layout -> attention loads become coalesced 64B rows.
// ---------------------------------------------------------------------------
__global__ void k_transpose_qkv(const float* __restrict__ W, short* __restrict__ WT) {
    int idx = blockIdx.x * 256 + threadIdx.x;
    if (idx >= 192 * 576) return;
    int n = idx / 192, kk = idx % 192;           // n = new col, kk = K row
    int d = n & 31, hh = (n >> 5) % 6, k3 = n / 192;
    int oc = d * 18 + k3 * 6 + hh;               // original column
    WT[idx] = f2bf(W[kk * 576 + oc]);
}

// ---------------------------------------------------------------------------
// Fused depthwise-3x3 CPE (residual) + LayerNorm — branchless sliding window.
// One wave owns 8 consecutive tokens along w (Wd = 7*8). Loads the 3x10
// float4 halo window with clamped addresses (30 loads in flight), register
// edge masks, register stencil FMAs, 8 interleaved shfl reductions.
// ADDP=1: input y = xin + proj (proj is bf16 in WINDOW-row order; per-halo
// token the window row is wave-uniform arithmetic, channel reads contiguous).
// ---------------------------------------------------------------------------
template<int ADDP>
__global__ void __launch_bounds__(256) k_cpe_ln(
    const float* __restrict__ xin, const float* __restrict__ wconv,
    const float* __restrict__ bconv, const float* __restrict__ g,
    const float* __restrict__ beta, float* __restrict__ ysum_out,
    short* __restrict__ ln_out, int windowed, const short* __restrict__ proj)
{
    const int lane = threadIdx.x & 63;
    const int wv   = threadIdx.x >> 6;
    const bool act = lane < 48;
    const int c4   = (lane < 48 ? lane : lane - 16) * 4;   // clamped channel base

    const floatx4 zf = {0.f, 0.f, 0.f, 0.f};
    float wreg[36];
    #pragma unroll
    for (int i = 0; i < 9; ++i)
        *(floatx4*)&wreg[i * 4] = *(const floatx4*)(wconv + c4 * 9 + i * 4);
    const floatx4 gv  = *(const floatx4*)(g + c4);
    const floatx4 bv  = *(const floatx4*)(beta + c4);
    const floatx4 bcv = *(const floatx4*)(bconv + c4);

    // wave -> (b, h, w0): 8-token run along w
    const int W = xcd_swz(blockIdx.x, gridDim.x) * 4 + wv;
    const int b = W / (Hh * 7);
    const int rem = W % (Hh * 7);
    const int h = rem / 7, wslot = rem % 7;
    const int w0 = wslot * 8;

    // ---- load 3x10 halo window, clamped addresses, zero branches ----
    floatx4 r[3][10];
    const int hy0 = (h > 0) ? h - 1 : 0;
    const int hy2 = (h < Hh - 1) ? h + 1 : Hh - 1;
    const int hys[3] = {hy0, h, hy2};
    #pragma unroll
    for (int dy = 0; dy < 3; ++dy) {
        const int hy = hys[dy];
        const float* rp = xin + ((size_t)b * (Hh * Wd) + hy * Wd) * Cc + c4;
        #pragma unroll
        for (int j = 0; j < 10; ++j) {
            int wx = w0 - 1 + j;
            int wc = (wx < 0) ? 0 : ((wx > Wd - 1) ? Wd - 1 : wx);
            floatx4 v = *(const floatx4*)(rp + wc * Cc);
            if (ADDP) {
                // window-row index of token (b, hy, wc)
                int prow = (b * 64 + (hy & 7) * 8 + (wc & 7)) * 49
                         + (hy >> 3) * 7 + (wc >> 3);
                s4v pv = *(const s4v*)(proj + (size_t)prow * Cc + c4);
                #pragma unroll
                for (int q = 0; q < 4; ++q) v[q] += bf2f(pv[q]);
            }
            r[dy][j] = v;
        }
    }
    // edge masks (wave-uniform, register-only)
    if (h == 0) {
        #pragma unroll
        for (int j = 0; j < 10; ++j) r[0][j] = zf;
    }
    if (h == Hh - 1) {
        #pragma unroll
        for (int j = 0; j < 10; ++j) r[2][j] = zf;
    }
    if (w0 == 0)      { r[0][0] = zf; r[1][0] = zf; r[2][0] = zf; }
    if (w0 == Wd - 8) { r[0][9] = zf; r[1][9] = zf; r[2][9] = zf; }

    // ---- stencil: 8 tokens, pure register FMAs ----
    floatx4 val[8];
    #pragma unroll
    for (int tk = 0; tk < 8; ++tk) {
        floatx4 a = bcv;
        #pragma unroll
        for (int dy = 0; dy < 3; ++dy) {
            #pragma unroll
            for (int dx = 0; dx < 3; ++dx) {
                const int t = dy * 3 + dx;
                floatx4 v = r[dy][tk + dx];
                #pragma unroll
                for (int j = 0; j < 4; ++j)
                    a[j] += wreg[j * 9 + t] * v[j];
            }
        }
        floatx4 xc = r[1][tk + 1];               // center (residual input y)
        #pragma unroll
        for (int j = 0; j < 4; ++j) val[tk][j] = xc[j] + a[j];
    }

    // ---- 8 interleaved LN reductions (lanes 48-63 contribute zero) ----
    float s[8], s2[8];
    #pragma unroll
    for (int tk = 0; tk < 8; ++tk) {
        float a = val[tk][0] + val[tk][1] + val[tk][2] + val[tk][3];
        float a2 = val[tk][0]*val[tk][0] + val[tk][1]*val[tk][1]
                 + val[tk][2]*val[tk][2] + val[tk][3]*val[tk][3];
        s[tk]  = act ? a  : 0.f;
        s2[tk] = act ? a2 : 0.f;
    }
    #pragma unroll
    for (int off = 1; off < 64; off <<= 1) {
        #pragma unroll
        for (int tk = 0; tk < 8; ++tk) {
            s[tk]  += __shfl_xor(s[tk],  off, 64);
            s2[tk] += __shfl_xor(s2[tk], off, 64);
        }
    }

    // ---- epilogue: residual store + LN bf16 store ----
    const int blk0 = (b * Hh + h) * Wd + w0;
    #pragma unroll
    for (int tk = 0; tk < 8; ++tk) {
        const float mean = s[tk] * (1.0f / Cc);
        const float var  = s2[tk] * (1.0f / Cc) - mean * mean;
        const float rs   = rsqrtf(var + 1e-5f);
        int rr;
        if (windowed) {
            int win = b * 64 + (h & 7) * 8 + tk;     // (w0+tk)&7 == tk
            int pos = (h >> 3) * 7 + wslot;          // (w0+tk)>>3 == wslot
            rr = win * 49 + pos;
        } else {
            rr = blk0 + tk;
        }
        if (act) {
            *(floatx4*)(ysum_out + (size_t)(blk0 + tk) * Cc + c4) = val[tk];
            s4v o;
            #pragma unroll
            for (int j = 0; j < 4; ++j)
                o[j] = f2bf((val[tk][j] - mean) * rs * gv[j] + bv[j]);
            *(s4v*)(ln_out + (size_t)rr * Cc + c4) = o;
        }
    }
}

// ---------------------------------------------------------------------------
// Tiled MFMA GEMM: BM=256, BN=64, BK=32, 256 thr / 4 waves.
// m97-equal per-iter shape: per wave 16 MFMA : 8 ds_read_b128 : 2 barriers
// (was 8:6:2 at BM=128 — barrier drain amortized over 2x the MFMA work).
// Staging via global_load_lds 16B: per iter 4 A-quarter DMAs + 1 B DMA per
// wave, lane-linear LDS dest per the DMA contract.
// EPI==0: qkv output (bf16, permuted-column bias remap)
// EPI==2: fc1 + exact GELU, bf16 stride HIDN
// EPI==3: fc2, += into fp32 out (token order)
// EPI==4: proj, dense bf16 write in window-row order (residual added later)
// ---------------------------------------------------------------------------
template<int K, int EPI>
__global__ void __launch_bounds__(256) k_gemm_tiled(
    const short* __restrict__ A, const short* __restrict__ BT,
    const float* __restrict__ bias, void* __restrict__ outp)
{
    __shared__ __align__(16) short As[256 * 32];
    __shared__ __align__(16) short Bs[64 * 32];
    const int tid = threadIdx.x;
    const int gx = gridDim.x;
    const int flat = blockIdx.y * gx + blockIdx.x;
    const int swz = xcd_swz(flat, gx * gridDim.y);
    const int n0 = (swz % gx) * 64;
    const int m0 = (swz / gx) * 256;
    const int w = tid >> 6, lane = tid & 63;
    const int lcol = lane & 15, quad = lane >> 4;

    floatx4 acc[4][4];
    #pragma unroll
    for (int mi = 0; mi < 4; ++mi)
        #pragma unroll
        for (int ni = 0; ni < 4; ++ni) acc[mi][ni] = (floatx4){0, 0, 0, 0};

    // staging: wave w covers A rows [w*64, w*64+64) in 4 chunks of 16 rows,
    // and B rows [w*16, w*16+16). Per-lane: row += lane>>2, colblk = lane&3.
    const int srow = lane >> 2, scol = (lane & 3) * 8;
    const short* agp = A + (size_t)(m0 + w * 64 + srow) * K + scol;
    const short* bgp = BT + (size_t)(n0 + w * 16 + srow) * K + scol;
    short* asw = As + (w * 64) * 32 + lane * 8;     // lane-linear dest
    short* bsw = Bs + (w * 16) * 32 + lane * 8;

    const short* ard0 = As + (w * 64 + lcol) * 32 + quad * 8;
    const short* brd  = Bs + lcol * 32 + quad * 8;

    for (int k0 = 0; k0 < K; k0 += 32) {
        __syncthreads();                  // prior reads of As/Bs complete
        #pragma unroll
        for (int c = 0; c < 4; ++c)
            gl_lds16(agp + (size_t)c * 16 * K + k0, asw + c * 16 * 32);
        gl_lds16(bgp + k0, bsw);
        __syncthreads();                  // drains vmcnt -> LDS ready
        short8 a0 = *(const short8*)(ard0);
        short8 a1 = *(const short8*)(ard0 + 16 * 32);
        short8 a2 = *(const short8*)(ard0 + 32 * 32);
        short8 a3 = *(const short8*)(ard0 + 48 * 32);
        #pragma unroll
        for (int ni = 0; ni < 4; ++ni) {
            short8 b = *(const short8*)(brd + ni * 16 * 32);
            acc[0][ni] = __builtin_amdgcn_mfma_f32_16x16x32_bf16(a0, b, acc[0][ni], 0, 0, 0);
            acc[1][ni] = __builtin_amdgcn_mfma_f32_16x16x32_bf16(a1, b, acc[1][ni], 0, 0, 0);
            acc[2][ni] = __builtin_amdgcn_mfma_f32_16x16x32_bf16(a2, b, acc[2][ni], 0, 0, 0);
            acc[3][ni] = __builtin_amdgcn_mfma_f32_16x16x32_bf16(a3, b, acc[3][ni], 0, 0, 0);
        }
    }

    #pragma unroll
    for (int mi = 0; mi < 4; ++mi) {
        #pragma unroll
        for (int ni = 0; ni < 4; ++ni) {
            int col = n0 + ni * 16 + lcol;
            float bv;
            if (EPI == 0) {
                // permuted-column layout: col = k*192 + h*32 + d
                int d = col & 31, hh = (col >> 5) % 6, k3 = col / 192;
                bv = bias[d * 18 + k3 * 6 + hh];
            } else {
                bv = bias[col];
            }
            #pragma unroll
            for (int t = 0; t < 4; ++t) {
                int row = m0 + w * 64 + mi * 16 + quad * 4 + t;
                float v = acc[mi][ni][t] + bv;
                if (EPI == 0) {
                    ((short*)outp)[(size_t)row * 576 + col] = f2bf(v);
                } else if (EPI == 2) {
                    float gl = 0.5f * v * (1.0f + erff(v * 0.70710678118654752f));
                    ((short*)outp)[(size_t)row * HIDN + col] = f2bf(gl);
                } else if (EPI == 3) {
                    ((float*)outp)[(size_t)row * Cc + col] += v;
                } else {
                    ((short*)outp)[(size_t)row * Cc + col] = f2bf(v);
                }
            }
        }
    }
}

// ---------------------------------------------------------------------------
// MFMA window attention: one wave (64 thr) per (window, head).
// qkvbuf column layout is [k*192 + h*32 + d] -> Q/K/V rows for a given
// (k,h) are 32 consecutive shorts (64B, 64B-aligned). Staging loads are
// short8, fully coalesced. LDS overlay: P reuses dead Q/K region.
// ---------------------------------------------------------------------------
__global__ void __launch_bounds__(64) k_attn(
    const short* __restrict__ C, short* __restrict__ aout)
{
    int h = blockIdx.x, win = blockIdx.y;
    int lane = threadIdx.x;
    int lcol = lane & 15, quad = lane >> 4;
    __shared__ __align__(16) short buf[7424];
    short* Q  = buf;            // [64*40]
    short* Kb = buf + 2560;     // [64*40]
    short* Vt = buf + 5120;     // [32*72]
    short* P  = buf;            // [64*72] overlays Q+Kb after S-phase

    const short8 z8 = {0, 0, 0, 0, 0, 0, 0, 0};
    const size_t wbase = (size_t)win * 49 * 576;
    const int hq = h * 32;
    const int pr = lane >> 2, d8 = (lane & 3) * 8;

    // Q and K: 16 rows per wave-iteration, 64B contiguous per row
    #pragma unroll
    for (int it = 0; it < 4; ++it) {
        int pp = pr + it * 16;
        bool ok = pp < 49;
        size_t ro = wbase + (size_t)(ok ? pp : 0) * 576 + hq + d8;
        short8 vq = ok ? *(const short8*)(C + ro)       : z8;
        short8 vk = ok ? *(const short8*)(C + ro + 192) : z8;
        *(short8*)(Q  + pp * 40 + d8) = vq;
        *(short8*)(Kb + pp * 40 + d8) = vk;
    }
    // V: coalesced row loads, transposed scatter into Vt[d][p]
    #pragma unroll
    for (int it = 0; it < 4; ++it) {
        int pp = pr + it * 16;
        bool ok = pp < 49;
        size_t ro = wbase + (size_t)(ok ? pp : 0) * 576 + 384 + hq + d8;
        short8 vv = ok ? *(const short8*)(C + ro) : z8;
        #pragma unroll
        for (int j = 0; j < 8; ++j)
            Vt[(d8 + j) * 72 + pp] = vv[j];
    }

    floatx4 s[4][4];
    #pragma unroll
    for (int mi = 0; mi < 4; ++mi) {
        short8 aq = *(const short8*)(Q + (mi * 16 + lcol) * 40 + quad * 8);
        #pragma unroll
        for (int ni = 0; ni < 4; ++ni) {
            short8 bk = *(const short8*)(Kb + (ni * 16 + lcol) * 40 + quad * 8);
            floatx4 z = {0, 0, 0, 0};
            s[mi][ni] = __builtin_amdgcn_mfma_f32_16x16x32_bf16(aq, bk, z, 0, 0, 0);
        }
    }

    const float scale = 0.17677669529663688f;   // 1/sqrt(32)
    #pragma unroll
    for (int mi = 0; mi < 4; ++mi) {
        #pragma unroll
        for (int reg = 0; reg < 4; ++reg) {
            float vv[4];
            float mx = -3e38f;
            #pragma unroll
            for (int ni = 0; ni < 4; ++ni) {
                int col = ni * 16 + lcol;
                float v = (col < 49) ? s[mi][ni][reg] * scale : -3e38f;
                vv[ni] = v;
                mx = fmaxf(mx, v);
            }
            #pragma unroll
            for (int off = 1; off < 16; off <<= 1)
                mx = fmaxf(mx, __shfl_xor(mx, off, 64));
            float sum = 0.f;
            #pragma unroll
            for (int ni = 0; ni < 4; ++ni) {
                int col = ni * 16 + lcol;
                float e = (col < 49) ? __expf(vv[ni] - mx) : 0.f;
                vv[ni] = e;
                sum += e;
            }
            #pragma unroll
            for (int off = 1; off < 16; off <<= 1)
                sum += __shfl_xor(sum, off, 64);
            float inv = 1.0f / sum;
            int row = mi * 16 + quad * 4 + reg;
            #pragma unroll
            for (int ni = 0; ni < 4; ++ni)
                P[row * 72 + ni * 16 + lcol] = f2bf(vv[ni] * inv);
        }
    }

    #pragma unroll
    for (int mi = 0; mi < 4; ++mi) {
        short8 a0 = *(const short8*)(P + (mi * 16 + lcol) * 72 + quad * 8);
        short8 a1 = *(const short8*)(P + (mi * 16 + lcol) * 72 + 32 + quad * 8);
        #pragma unroll
        for (int nd = 0; nd < 2; ++nd) {
            short8 b0 = *(const short8*)(Vt + (nd * 16 + lcol) * 72 + quad * 8);
            short8 b1 = *(const short8*)(Vt + (nd * 16 + lcol) * 72 + 32 + quad * 8);
            floatx4 z = {0, 0, 0, 0};
            floatx4 o = __builtin_amdgcn_mfma_f32_16x16x32_bf16(a0, b0, z, 0, 0, 0);
            o = __builtin_amdgcn_mfma_f32_16x16x32_bf16(a1, b1, o, 0, 0, 0);
            #pragma unroll
            for (int reg = 0; reg < 4; ++reg) {
                int row = mi * 16 + quad * 4 + reg;
                if (row < 49)
                    aout[((size_t)win * 49 + row) * Cc + h * HDim + nd * 16 + lcol] =
                        f2bf(o[reg]);
            }
        }
    }
}

// ---------------------------------------------------------------------------
extern "C" void kernel_launch(void* const* d_in, const int* in_sizes, int n_in,
                              void* d_out, int out_size, void* d_ws, size_t ws_size,
                              hipStream_t stream)
{
    (void)in_sizes; (void)n_in; (void)out_size; (void)ws_size;
    const float* x      = (const float*)d_in[0];
    const float* cpe0_w = (const float*)d_in[3];
    const float* cpe0_b = (const float*)d_in[4];
    const float* cpe1_w = (const float*)d_in[5];
    const float* cpe1_b = (const float*)d_in[6];
    const float* n1_g   = (const float*)d_in[7];
    const float* n1_b   = (const float*)d_in[8];
    const float* qkv_w  = (const float*)d_in[9];
    const float* qkv_b  = (const float*)d_in[10];
    const float* proj_w = (const float*)d_in[11];
    const float* proj_b = (const float*)d_in[12];
    const float* n2_g   = (const float*)d_in[13];
    const float* n2_b   = (const float*)d_in[14];
    const float* fc1_w  = (const float*)d_in[15];
    const float* fc1_b  = (const float*)d_in[16];
    const float* fc2_w  = (const float*)d_in[17];
    const float* fc2_b  = (const float*)d_in[18];
    float* out = (float*)d_out;

    char* ws = (char*)d_ws;
    float* shortcut = (float*)ws;                     // 77,070,336  (fp32 Tt*192)
    short* lnbuf    = (short*)(ws + 77070336);        // 38,535,168  (bf16 Tt*192)
    short* qkvbuf   = (short*)(ws + 115605504);       // 115,605,504 (bf16 Tt*576)
    short* attnout  = (short*)(ws + 231211008);       // 38,535,168
    short* projbuf  = qkvbuf;                         // overlays dead qkvbuf
    short* h1       = qkvbuf;                         // fc1 out overlays proj+attn
    short* wqkvT    = (short*)(ws + 269746176);       // 221,184
    short* wprojT   = (short*)(ws + 269967360);       // 73,728
    short* wfc1T    = (short*)(ws + 270041088);       // 294,912
    short* wfc2T    = (short*)(ws + 270336000);       // 294,912

    k_transpose_qkv<<<dim3((192 * 576 + 255) / 256), dim3(256), 0, stream>>>(qkv_w, wqkvT);
    k_transpose<<<dim3((192 * 192 + 255) / 256), dim3(256), 0, stream>>>(proj_w, wprojT, 192, 192);
    k_transpose<<<dim3((192 * 768 + 255) / 256), dim3(256), 0, stream>>>(fc1_w, wfc1T, 192, 768);
    k_transpose<<<dim3((768 * 192 + 255) / 256), dim3(256), 0, stream>>>(fc2_w, wfc2T, 768, 192);

    k_cpe_ln<0><<<dim3(Tt / 32), dim3(256), 0, stream>>>(x, cpe0_w, cpe0_b, n1_g, n1_b,
                                                         shortcut, lnbuf, 1, nullptr);
    k_gemm_tiled<192, 0><<<dim3(9, Tt / 256), dim3(256), 0, stream>>>(lnbuf, wqkvT, qkv_b, qkvbuf);
    k_attn<<<dim3(NHh, NWIN), dim3(64), 0, stream>>>(qkvbuf, attnout);
    // proj: dense bf16 write in window-row order (no RMW scatter)
    k_gemm_tiled<192, 4><<<dim3(3, Tt / 256), dim3(256), 0, stream>>>(attnout, wprojT, proj_b, projbuf);
    // cpe_ln#2 fuses the residual add y = shortcut + proj
    k_cpe_ln<1><<<dim3(Tt / 32), dim3(256), 0, stream>>>(shortcut, cpe1_w, cpe1_b, n2_g, n2_b,
                                                         out, lnbuf, 0, projbuf);
    k_gemm_tiled<192, 2><<<dim3(12, Tt / 256), dim3(256), 0, stream>>>(lnbuf, wfc1T, fc1_b, h1);
    k_gemm_tiled<768, 3><<<dim3(3, Tt / 256), dim3(256), 0, stream>>>(h1, wfc2T, fc2_b, out);
}

// Round 11
// 560.418 us; speedup vs baseline: 1.0170x; 1.0170x over previous
//
#include <hip/hip_runtime.h>
#include <hip/hip_bf16.h>
#include <math.h>

// Problem constants
#define Bn   32
#define Hh   56
#define Wd   56
#define Cc   192
#define NHh  6
#define HDim 32
#define HIDN 768
#define Tt   (Bn*Hh*Wd)          // 100352 tokens
#define NWIN (Bn*64)             // 2048 windows

typedef __attribute__((ext_vector_type(8))) short short8;
typedef __attribute__((ext_vector_type(4))) short s4v;
typedef __attribute__((ext_vector_type(4))) float floatx4;

__device__ __forceinline__ short f2bf(float f) {
    unsigned u = __float_as_uint(f);
    u += 0x7fffu + ((u >> 16) & 1u);     // round-to-nearest-even
    return (short)(u >> 16);
}
__device__ __forceinline__ float bf2f(short s) {
    return __uint_as_float(((unsigned)(unsigned short)s) << 16);
}

// async global->LDS, 16B per lane. LDS dest is wave-uniform base + lane*16;
// caller must pass a lane-linear LDS pointer (ptr = base + lane*8 shorts).
__device__ __forceinline__ void gl_lds16(const short* g, short* l) {
    __builtin_amdgcn_global_load_lds(
        (const __attribute__((address_space(1))) unsigned int*)g,
        (__attribute__((address_space(3))) unsigned int*)l,
        16, 0, 0);
}

// XCD-aware bijective block swizzle (requires nb % 8 == 0): each XCD gets a
// contiguous chunk of the flat block range -> neighbor blocks share an L2.
__device__ __forceinline__ int xcd_swz(int bid, int nb) {
    return (bid & 7) * (nb >> 3) + (bid >> 3);
}

// ---------------------------------------------------------------------------
// Weight transpose + bf16 convert: W[K,N] fp32 -> WT[N,K] bf16
// ---------------------------------------------------------------------------
__global__ void k_transpose(const float* __restrict__ W, short* __restrict__ WT,
                            int K, int N) {
    int idx = blockIdx.x * 256 + threadIdx.x;
    if (idx >= K * N) return;
    int n = idx / K, k = idx % K;        // coalesced writes
    WT[idx] = f2bf(W[k * N + n]);
}

// ---------------------------------------------------------------------------
// QKV weight transpose with COLUMN PERMUTATION:
// reference column order is (d k h): col = d*18 + k*6 + h.
// We emit new order col' = k*192 + h*32 + d so the GEMM writes qkvbuf in a
// per-(k,head) contiguous-d layout -> attention loads become coalesced 64B rows.
// ---------------------------------------------------------------------------
__global__ void k_transpose_qkv(const float* __restrict__ W, short* __restrict__ WT) {
    int idx = blockIdx.x * 256 + threadIdx.x;
    if (idx >= 192 * 576) return;
    int n = idx / 192, kk = idx % 192;           // n = new col, kk = K row
    int d = n & 31, hh = (n >> 5) % 6, k3 = n / 192;
    int oc = d * 18 + k3 * 6 + hh;               // original column
    WT[idx] = f2bf(W[kk * 576 + oc]);
}

// ---------------------------------------------------------------------------
// Fused depthwise-3x3 CPE (residual) + LayerNorm — branchless sliding window.
// One wave owns 8 consecutive tokens along w (Wd = 7*8). Loads the 3x10
// float4 halo window with clamped addresses (30 loads in flight), register
// edge masks, register stencil FMAs, 8 interleaved shfl reductions.
// ADDP=1: input y = xin + proj (proj is bf16 in WINDOW-row order; per-halo
// token the window row is wave-uniform arithmetic, channel reads contiguous).
// ---------------------------------------------------------------------------
template<int ADDP>
__global__ void __launch_bounds__(256) k_cpe_ln(
    const float* __restrict__ xin, const float* __restrict__ wconv,
    const float* __restrict__ bconv, const float* __restrict__ g,
    const float* __restrict__ beta, float* __restrict__ ysum_out,
    short* __restrict__ ln_out, int windowed, const short* __restrict__ proj)
{
    const int lane = threadIdx.x & 63;
    const int wv   = threadIdx.x >> 6;
    const bool act = lane < 48;
    const int c4   = (lane < 48 ? lane : lane - 16) * 4;   // clamped channel base

    const floatx4 zf = {0.f, 0.f, 0.f, 0.f};
    float wreg[36];
    #pragma unroll
    for (int i = 0; i < 9; ++i)
        *(floatx4*)&wreg[i * 4] = *(const floatx4*)(wconv + c4 * 9 + i * 4);
    const floatx4 gv  = *(const floatx4*)(g + c4);
    const floatx4 bv  = *(const floatx4*)(beta + c4);
    const floatx4 bcv = *(const floatx4*)(bconv + c4);

    // wave -> (b, h, w0): 8-token run along w
    const int W = xcd_swz(blockIdx.x, gridDim.x) * 4 + wv;
    const int b = W / (Hh * 7);
    const int rem = W % (Hh * 7);
    const int h = rem / 7, wslot = rem % 7;
    const int w0 = wslot * 8;

    // ---- load 3x10 halo window, clamped addresses, zero branches ----
    floatx4 r[3][10];
    const int hy0 = (h > 0) ? h - 1 : 0;
    const int hy2 = (h < Hh - 1) ? h + 1 : Hh - 1;
    const int hys[3] = {hy0, h, hy2};
    #pragma unroll
    for (int dy = 0; dy < 3; ++dy) {
        const int hy = hys[dy];
        const float* rp = xin + ((size_t)b * (Hh * Wd) + hy * Wd) * Cc + c4;
        #pragma unroll
        for (int j = 0; j < 10; ++j) {
            int wx = w0 - 1 + j;
            int wc = (wx < 0) ? 0 : ((wx > Wd - 1) ? Wd - 1 : wx);
            floatx4 v = *(const floatx4*)(rp + wc * Cc);
            if (ADDP) {
                // window-row index of token (b, hy, wc)
                int prow = (b * 64 + (hy & 7) * 8 + (wc & 7)) * 49
                         + (hy >> 3) * 7 + (wc >> 3);
                s4v pv = *(const s4v*)(proj + (size_t)prow * Cc + c4);
                #pragma unroll
                for (int q = 0; q < 4; ++q) v[q] += bf2f(pv[q]);
            }
            r[dy][j] = v;
        }
    }
    // edge masks (wave-uniform, register-only)
    if (h == 0) {
        #pragma unroll
        for (int j = 0; j < 10; ++j) r[0][j] = zf;
    }
    if (h == Hh - 1) {
        #pragma unroll
        for (int j = 0; j < 10; ++j) r[2][j] = zf;
    }
    if (w0 == 0)      { r[0][0] = zf; r[1][0] = zf; r[2][0] = zf; }
    if (w0 == Wd - 8) { r[0][9] = zf; r[1][9] = zf; r[2][9] = zf; }

    // ---- stencil: 8 tokens, pure register FMAs ----
    floatx4 val[8];
    #pragma unroll
    for (int tk = 0; tk < 8; ++tk) {
        floatx4 a = bcv;
        #pragma unroll
        for (int dy = 0; dy < 3; ++dy) {
            #pragma unroll
            for (int dx = 0; dx < 3; ++dx) {
                const int t = dy * 3 + dx;
                floatx4 v = r[dy][tk + dx];
                #pragma unroll
                for (int j = 0; j < 4; ++j)
                    a[j] += wreg[j * 9 + t] * v[j];
            }
        }
        floatx4 xc = r[1][tk + 1];               // center (residual input y)
        #pragma unroll
        for (int j = 0; j < 4; ++j) val[tk][j] = xc[j] + a[j];
    }

    // ---- 8 interleaved LN reductions (lanes 48-63 contribute zero) ----
    float s[8], s2[8];
    #pragma unroll
    for (int tk = 0; tk < 8; ++tk) {
        float a = val[tk][0] + val[tk][1] + val[tk][2] + val[tk][3];
        float a2 = val[tk][0]*val[tk][0] + val[tk][1]*val[tk][1]
                 + val[tk][2]*val[tk][2] + val[tk][3]*val[tk][3];
        s[tk]  = act ? a  : 0.f;
        s2[tk] = act ? a2 : 0.f;
    }
    #pragma unroll
    for (int off = 1; off < 64; off <<= 1) {
        #pragma unroll
        for (int tk = 0; tk < 8; ++tk) {
            s[tk]  += __shfl_xor(s[tk],  off, 64);
            s2[tk] += __shfl_xor(s2[tk], off, 64);
        }
    }

    // ---- epilogue: residual store + LN bf16 store ----
    const int blk0 = (b * Hh + h) * Wd + w0;
    #pragma unroll
    for (int tk = 0; tk < 8; ++tk) {
        const float mean = s[tk] * (1.0f / Cc);
        const float var  = s2[tk] * (1.0f / Cc) - mean * mean;
        const float rs   = rsqrtf(var + 1e-5f);
        int rr;
        if (windowed) {
            int win = b * 64 + (h & 7) * 8 + tk;     // (w0+tk)&7 == tk
            int pos = (h >> 3) * 7 + wslot;          // (w0+tk)>>3 == wslot
            rr = win * 49 + pos;
        } else {
            rr = blk0 + tk;
        }
        if (act) {
            *(floatx4*)(ysum_out + (size_t)(blk0 + tk) * Cc + c4) = val[tk];
            s4v o;
            #pragma unroll
            for (int j = 0; j < 4; ++j)
                o[j] = f2bf((val[tk][j] - mean) * rs * gv[j] + bv[j]);
            *(s4v*)(ln_out + (size_t)rr * Cc + c4) = o;
        }
    }
}

// ---------------------------------------------------------------------------
// Tiled MFMA GEMM: BM=128, BN=64, BK=32, 256 thr / 4 waves.
// DOUBLE-BUFFERED 2-phase pipeline (T3 minimum template): issue next tile's
// global_load_lds right after the barrier, BEFORE computing the current tile
// -> DMA latency hides under ds_read+MFMA; ONE barrier per K-iter.
// Loop unrolled x2 so buffer indices are compile-time (K/32 is even: 6, 24).
// EPI==0: qkv output (bf16, permuted-column bias remap)
// EPI==2: fc1 + exact GELU, bf16 stride HIDN
// EPI==3: fc2, += into fp32 out (token order)
// EPI==4: proj, dense bf16 write in window-row order (residual added later)
// ---------------------------------------------------------------------------
template<int K, int EPI>
__global__ void __launch_bounds__(256) k_gemm_tiled(
    const short* __restrict__ A, const short* __restrict__ BT,
    const float* __restrict__ bias, void* __restrict__ outp)
{
    __shared__ __align__(16) short As[2][128 * 32];
    __shared__ __align__(16) short Bs[2][64 * 32];
    const int tid = threadIdx.x;
    const int gx = gridDim.x;
    const int flat = blockIdx.y * gx + blockIdx.x;
    const int swz = xcd_swz(flat, gx * gridDim.y);
    const int n0 = (swz % gx) * 64;
    const int m0 = (swz / gx) * 128;
    const int w = tid >> 6, lane = tid & 63;
    const int lcol = lane & 15, quad = lane >> 4;

    floatx4 acc[2][4];
    #pragma unroll
    for (int mi = 0; mi < 2; ++mi)
        #pragma unroll
        for (int ni = 0; ni < 4; ++ni) acc[mi][ni] = (floatx4){0, 0, 0, 0};

    const int ar = tid >> 2, ac = (tid & 3) * 8;
    const short* agp  = A + (size_t)(m0 + ar) * K + ac;
    const short* agp2 = A + (size_t)(m0 + 64 + ar) * K + ac;
    const short* bgp  = BT + (size_t)(n0 + ar) * K + ac;

    const int aoff = w * 32 + lcol;      // fragment row for this lane

    // prologue: stage tile 0 into buffer 0
    gl_lds16(agp, &As[0][tid * 8]);
    gl_lds16(agp2, &As[0][64 * 32 + tid * 8]);
    gl_lds16(bgp, &Bs[0][tid * 8]);

    #pragma unroll 2
    for (int t = 0; t < K / 32; ++t) {
        const int b = t & 1;
        __syncthreads();                 // drains DMA for buf b; prior reads done
        if (t + 1 < K / 32) {            // issue next tile into other buffer
            const int k1 = (t + 1) * 32;
            gl_lds16(agp + k1, &As[b ^ 1][tid * 8]);
            gl_lds16(agp2 + k1, &As[b ^ 1][64 * 32 + tid * 8]);
            gl_lds16(bgp + k1, &Bs[b ^ 1][tid * 8]);
        }
        short8 a0 = *(const short8*)&As[b][aoff * 32 + quad * 8];
        short8 a1 = *(const short8*)&As[b][(aoff + 16) * 32 + quad * 8];
        #pragma unroll
        for (int ni = 0; ni < 4; ++ni) {
            short8 bb = *(const short8*)&Bs[b][(ni * 16 + lcol) * 32 + quad * 8];
            acc[0][ni] = __builtin_amdgcn_mfma_f32_16x16x32_bf16(a0, bb, acc[0][ni], 0, 0, 0);
            acc[1][ni] = __builtin_amdgcn_mfma_f32_16x16x32_bf16(a1, bb, acc[1][ni], 0, 0, 0);
        }
    }

    #pragma unroll
    for (int mi = 0; mi < 2; ++mi) {
        #pragma unroll
        for (int ni = 0; ni < 4; ++ni) {
            int col = n0 + ni * 16 + lcol;
            float bv;
            if (EPI == 0) {
                // permuted-column layout: col = k*192 + h*32 + d
                int d = col & 31, hh = (col >> 5) % 6, k3 = col / 192;
                bv = bias[d * 18 + k3 * 6 + hh];
            } else {
                bv = bias[col];
            }
            #pragma unroll
            for (int t = 0; t < 4; ++t) {
                int row = m0 + w * 32 + mi * 16 + quad * 4 + t;
                float v = acc[mi][ni][t] + bv;
                if (EPI == 0) {
                    ((short*)outp)[(size_t)row * 576 + col] = f2bf(v);
                } else if (EPI == 2) {
                    float gl = 0.5f * v * (1.0f + erff(v * 0.70710678118654752f));
                    ((short*)outp)[(size_t)row * HIDN + col] = f2bf(gl);
                } else if (EPI == 3) {
                    ((float*)outp)[(size_t)row * Cc + col] += v;
                } else {
                    ((short*)outp)[(size_t)row * Cc + col] = f2bf(v);
                }
            }
        }
    }
}

// ---------------------------------------------------------------------------
// MFMA window attention: one wave (64 thr) per (window, head).
// qkvbuf column layout is [k*192 + h*32 + d] -> Q/K/V rows for a given
// (k,h) are 32 consecutive shorts (64B, 64B-aligned). Staging loads are
// short8, fully coalesced. LDS overlay: P reuses dead Q/K region.
// ---------------------------------------------------------------------------
__global__ void __launch_bounds__(64) k_attn(
    const short* __restrict__ C, short* __restrict__ aout)
{
    int h = blockIdx.x, win = blockIdx.y;
    int lane = threadIdx.x;
    int lcol = lane & 15, quad = lane >> 4;
    __shared__ __align__(16) short buf[7424];
    short* Q  = buf;            // [64*40]
    short* Kb = buf + 2560;     // [64*40]
    short* Vt = buf + 5120;     // [32*72]
    short* P  = buf;            // [64*72] overlays Q+Kb after S-phase

    const short8 z8 = {0, 0, 0, 0, 0, 0, 0, 0};
    const size_t wbase = (size_t)win * 49 * 576;
    const int hq = h * 32;
    const int pr = lane >> 2, d8 = (lane & 3) * 8;

    // Q and K: 16 rows per wave-iteration, 64B contiguous per row
    #pragma unroll
    for (int it = 0; it < 4; ++it) {
        int pp = pr + it * 16;
        bool ok = pp < 49;
        size_t ro = wbase + (size_t)(ok ? pp : 0) * 576 + hq + d8;
        short8 vq = ok ? *(const short8*)(C + ro)       : z8;
        short8 vk = ok ? *(const short8*)(C + ro + 192) : z8;
        *(short8*)(Q  + pp * 40 + d8) = vq;
        *(short8*)(Kb + pp * 40 + d8) = vk;
    }
    // V: coalesced row loads, transposed scatter into Vt[d][p]
    #pragma unroll
    for (int it = 0; it < 4; ++it) {
        int pp = pr + it * 16;
        bool ok = pp < 49;
        size_t ro = wbase + (size_t)(ok ? pp : 0) * 576 + 384 + hq + d8;
        short8 vv = ok ? *(const short8*)(C + ro) : z8;
        #pragma unroll
        for (int j = 0; j < 8; ++j)
            Vt[(d8 + j) * 72 + pp] = vv[j];
    }

    floatx4 s[4][4];
    #pragma unroll
    for (int mi = 0; mi < 4; ++mi) {
        short8 aq = *(const short8*)(Q + (mi * 16 + lcol) * 40 + quad * 8);
        #pragma unroll
        for (int ni = 0; ni < 4; ++ni) {
            short8 bk = *(const short8*)(Kb + (ni * 16 + lcol) * 40 + quad * 8);
            floatx4 z = {0, 0, 0, 0};
            s[mi][ni] = __builtin_amdgcn_mfma_f32_16x16x32_bf16(aq, bk, z, 0, 0, 0);
        }
    }

    const float scale = 0.17677669529663688f;   // 1/sqrt(32)
    #pragma unroll
    for (int mi = 0; mi < 4; ++mi) {
        #pragma unroll
        for (int reg = 0; reg < 4; ++reg) {
            float vv[4];
            float mx = -3e38f;
            #pragma unroll
            for (int ni = 0; ni < 4; ++ni) {
                int col = ni * 16 + lcol;
                float v = (col < 49) ? s[mi][ni][reg] * scale : -3e38f;
                vv[ni] = v;
                mx = fmaxf(mx, v);
            }
            #pragma unroll
            for (int off = 1; off < 16; off <<= 1)
                mx = fmaxf(mx, __shfl_xor(mx, off, 64));
            float sum = 0.f;
            #pragma unroll
            for (int ni = 0; ni < 4; ++ni) {
                int col = ni * 16 + lcol;
                float e = (col < 49) ? __expf(vv[ni] - mx) : 0.f;
                vv[ni] = e;
                sum += e;
            }
            #pragma unroll
            for (int off = 1; off < 16; off <<= 1)
                sum += __shfl_xor(sum, off, 64);
            float inv = 1.0f / sum;
            int row = mi * 16 + quad * 4 + reg;
            #pragma unroll
            for (int ni = 0; ni < 4; ++ni)
                P[row * 72 + ni * 16 + lcol] = f2bf(vv[ni] * inv);
        }
    }

    #pragma unroll
    for (int mi = 0; mi < 4; ++mi) {
        short8 a0 = *(const short8*)(P + (mi * 16 + lcol) * 72 + quad * 8);
        short8 a1 = *(const short8*)(P + (mi * 16 + lcol) * 72 + 32 + quad * 8);
        #pragma unroll
        for (int nd = 0; nd < 2; ++nd) {
            short8 b0 = *(const short8*)(Vt + (nd * 16 + lcol) * 72 + quad * 8);
            short8 b1 = *(const short8*)(Vt + (nd * 16 + lcol) * 72 + 32 + quad * 8);
            floatx4 z = {0, 0, 0, 0};
            floatx4 o = __builtin_amdgcn_mfma_f32_16x16x32_bf16(a0, b0, z, 0, 0, 0);
            o = __builtin_amdgcn_mfma_f32_16x16x32_bf16(a1, b1, o, 0, 0, 0);
            #pragma unroll
            for (int reg = 0; reg < 4; ++reg) {
                int row = mi * 16 + quad * 4 + reg;
                if (row < 49)
                    aout[((size_t)win * 49 + row) * Cc + h * HDim + nd * 16 + lcol] =
                        f2bf(o[reg]);
            }
        }
    }
}

// ---------------------------------------------------------------------------
extern "C" void kernel_launch(void* const* d_in, const int* in_sizes, int n_in,
                              void* d_out, int out_size, void* d_ws, size_t ws_size,
                              hipStream_t stream)
{
    (void)in_sizes; (void)n_in; (void)out_size; (void)ws_size;
    const float* x      = (const float*)d_in[0];
    const float* cpe0_w = (const float*)d_in[3];
    const float* cpe0_b = (const float*)d_in[4];
    const float* cpe1_w = (const float*)d_in[5];
    const float* cpe1_b = (const float*)d_in[6];
    const float* n1_g   = (const float*)d_in[7];
    const float* n1_b   = (const float*)d_in[8];
    const float* qkv_w  = (const float*)d_in[9];
    const float* qkv_b  = (const float*)d_in[10];
    const float* proj_w = (const float*)d_in[11];
    const float* proj_b = (const float*)d_in[12];
    const float* n2_g   = (const float*)d_in[13];
    const float* n2_b   = (const float*)d_in[14];
    const float* fc1_w  = (const float*)d_in[15];
    const float* fc1_b  = (const float*)d_in[16];
    const float* fc2_w  = (const float*)d_in[17];
    const float* fc2_b  = (const float*)d_in[18];
    float* out = (float*)d_out;

    char* ws = (char*)d_ws;
    float* shortcut = (float*)ws;                     // 77,070,336  (fp32 Tt*192)
    short* lnbuf    = (short*)(ws + 77070336);        // 38,535,168  (bf16 Tt*192)
    short* qkvbuf   = (short*)(ws + 115605504);       // 115,605,504 (bf16 Tt*576)
    short* attnout  = (short*)(ws + 231211008);       // 38,535,168
    short* projbuf  = qkvbuf;                         // overlays dead qkvbuf
    short* h1       = qkvbuf;                         // fc1 out overlays proj+attn
    short* wqkvT    = (short*)(ws + 269746176);       // 221,184
    short* wprojT   = (short*)(ws + 269967360);       // 73,728
    short* wfc1T    = (short*)(ws + 270041088);       // 294,912
    short* wfc2T    = (short*)(ws + 270336000);       // 294,912

    k_transpose_qkv<<<dim3((192 * 576 + 255) / 256), dim3(256), 0, stream>>>(qkv_w, wqkvT);
    k_transpose<<<dim3((192 * 192 + 255) / 256), dim3(256), 0, stream>>>(proj_w, wprojT, 192, 192);
    k_transpose<<<dim3((192 * 768 + 255) / 256), dim3(256), 0, stream>>>(fc1_w, wfc1T, 192, 768);
    k_transpose<<<dim3((768 * 192 + 255) / 256), dim3(256), 0, stream>>>(fc2_w, wfc2T, 768, 192);

    k_cpe_ln<0><<<dim3(Tt / 32), dim3(256), 0, stream>>>(x, cpe0_w, cpe0_b, n1_g, n1_b,
                                                         shortcut, lnbuf, 1, nullptr);
    k_gemm_tiled<192, 0><<<dim3(9, Tt / 128), dim3(256), 0, stream>>>(lnbuf, wqkvT, qkv_b, qkvbuf);
    k_attn<<<dim3(NHh, NWIN), dim3(64), 0, stream>>>(qkvbuf, attnout);
    // proj: dense bf16 write in window-row order (no RMW scatter)
    k_gemm_tiled<192, 4><<<dim3(3, Tt / 128), dim3(256), 0, stream>>>(attnout, wprojT, proj_b, projbuf);
    // cpe_ln#2 fuses the residual add y = shortcut + proj
    k_cpe_ln<1><<<dim3(Tt / 32), dim3(256), 0, stream>>>(shortcut, cpe1_w, cpe1_b, n2_g, n2_b,
                                                         out, lnbuf, 0, projbuf);
    k_gemm_tiled<192, 2><<<dim3(12, Tt / 128), dim3(256), 0, stream>>>(lnbuf, wfc1T, fc1_b, h1);
    k_gemm_tiled<768, 3><<<dim3(3, Tt / 128), dim3(256), 0, stream>>>(h1, wfc2T, fc2_b, out);
}

// Round 12
// 539.196 us; speedup vs baseline: 1.0571x; 1.0394x over previous
//
#include <hip/hip_runtime.h>
#include <hip/hip_bf16.h>
#include <math.h>

// Problem constants
#define Bn   32
#define Hh   56
#define Wd   56
#define Cc   192
#define NHh  6
#define HDim 32
#define HIDN 768
#define Tt   (Bn*Hh*Wd)          // 100352 tokens
#define NWIN (Bn*64)             // 2048 windows

typedef __attribute__((ext_vector_type(8))) short short8;
typedef __attribute__((ext_vector_type(4))) short s4v;
typedef __attribute__((ext_vector_type(4))) float floatx4;

__device__ __forceinline__ short f2bf(float f) {
    unsigned u = __float_as_uint(f);
    u += 0x7fffu + ((u >> 16) & 1u);     // round-to-nearest-even
    return (short)(u >> 16);
}
__device__ __forceinline__ float bf2f(short s) {
    return __uint_as_float(((unsigned)(unsigned short)s) << 16);
}

// async global->LDS, 16B per lane. LDS dest is wave-uniform base + lane*16;
// caller must pass a lane-linear LDS pointer (ptr = base + lane*8 shorts).
__device__ __forceinline__ void gl_lds16(const short* g, short* l) {
    __builtin_amdgcn_global_load_lds(
        (const __attribute__((address_space(1))) unsigned int*)g,
        (__attribute__((address_space(3))) unsigned int*)l,
        16, 0, 0);
}

// XCD-aware bijective block swizzle (requires nb % 8 == 0): each XCD gets a
// contiguous chunk of the flat block range -> neighbor blocks share an L2.
__device__ __forceinline__ int xcd_swz(int bid, int nb) {
    return (bid & 7) * (nb >> 3) + (bid >> 3);
}

// ---------------------------------------------------------------------------
// All four weight transposes in ONE launch (saves 3 launch overheads).
// qkv additionally gets the column permutation col' = k*192 + h*32 + d.
// ---------------------------------------------------------------------------
#define NQKV (192*576)
#define NPRJ (192*192)
#define NFC1 (192*768)
#define NFC2 (768*192)
__global__ void k_transpose_all(
    const float* __restrict__ qkv_w, const float* __restrict__ proj_w,
    const float* __restrict__ fc1_w, const float* __restrict__ fc2_w,
    short* __restrict__ wqkvT, short* __restrict__ wprojT,
    short* __restrict__ wfc1T, short* __restrict__ wfc2T)
{
    int idx = blockIdx.x * 256 + threadIdx.x;
    if (idx < NQKV) {
        int n = idx / 192, kk = idx % 192;
        int d = n & 31, hh = (n >> 5) % 6, k3 = n / 192;
        int oc = d * 18 + k3 * 6 + hh;
        wqkvT[idx] = f2bf(qkv_w[kk * 576 + oc]);
    } else if (idx < NQKV + NPRJ) {
        int i = idx - NQKV;
        int n = i / 192, k = i % 192;
        wprojT[i] = f2bf(proj_w[k * 192 + n]);
    } else if (idx < NQKV + NPRJ + NFC1) {
        int i = idx - NQKV - NPRJ;
        int n = i / 192, k = i % 192;
        wfc1T[i] = f2bf(fc1_w[k * 768 + n]);
    } else if (idx < NQKV + NPRJ + NFC1 + NFC2) {
        int i = idx - NQKV - NPRJ - NFC1;
        int n = i / 768, k = i % 768;
        wfc2T[i] = f2bf(fc2_w[k * 192 + n]);
    }
}

// ---------------------------------------------------------------------------
// Fused depthwise-3x3 CPE (residual) + LayerNorm — branchless sliding window.
// One wave owns 8 consecutive tokens along w (Wd = 7*8). Loads the 3x10
// halo window with clamped addresses (30 loads in flight), register edge
// masks, register stencil FMAs, 8 interleaved shfl reductions.
// ADDP=0: xin fp32 (x); ysum bf16 (shortcut).
// ADDP=1: xin bf16 (shortcut) + proj add (window-row order); ysum bf16 (ybuf).
// ---------------------------------------------------------------------------
template<int ADDP>
__global__ void __launch_bounds__(256) k_cpe_ln(
    const void* __restrict__ xin_, const float* __restrict__ wconv,
    const float* __restrict__ bconv, const float* __restrict__ g,
    const float* __restrict__ beta, short* __restrict__ ysum_out,
    short* __restrict__ ln_out, int windowed, const short* __restrict__ proj)
{
    const float* xf = (const float*)xin_;
    const short* xb = (const short*)xin_;
    const int lane = threadIdx.x & 63;
    const int wv   = threadIdx.x >> 6;
    const bool act = lane < 48;
    const int c4   = (lane < 48 ? lane : lane - 16) * 4;   // clamped channel base

    const floatx4 zf = {0.f, 0.f, 0.f, 0.f};
    float wreg[36];
    #pragma unroll
    for (int i = 0; i < 9; ++i)
        *(floatx4*)&wreg[i * 4] = *(const floatx4*)(wconv + c4 * 9 + i * 4);
    const floatx4 gv  = *(const floatx4*)(g + c4);
    const floatx4 bv  = *(const floatx4*)(beta + c4);
    const floatx4 bcv = *(const floatx4*)(bconv + c4);

    // wave -> (b, h, w0): 8-token run along w
    const int W = xcd_swz(blockIdx.x, gridDim.x) * 4 + wv;
    const int b = W / (Hh * 7);
    const int rem = W % (Hh * 7);
    const int h = rem / 7, wslot = rem % 7;
    const int w0 = wslot * 8;

    // ---- load 3x10 halo window, clamped addresses, zero branches ----
    floatx4 r[3][10];
    const int hy0 = (h > 0) ? h - 1 : 0;
    const int hy2 = (h < Hh - 1) ? h + 1 : Hh - 1;
    const int hys[3] = {hy0, h, hy2};
    #pragma unroll
    for (int dy = 0; dy < 3; ++dy) {
        const int hy = hys[dy];
        const size_t rowbase = ((size_t)b * (Hh * Wd) + hy * Wd) * Cc + c4;
        #pragma unroll
        for (int j = 0; j < 10; ++j) {
            int wx = w0 - 1 + j;
            int wc = (wx < 0) ? 0 : ((wx > Wd - 1) ? Wd - 1 : wx);
            floatx4 v;
            if (ADDP) {
                s4v xv = *(const s4v*)(xb + rowbase + (size_t)wc * Cc);
                int prow = (b * 64 + (hy & 7) * 8 + (wc & 7)) * 49
                         + (hy >> 3) * 7 + (wc >> 3);
                s4v pv = *(const s4v*)(proj + (size_t)prow * Cc + c4);
                #pragma unroll
                for (int q = 0; q < 4; ++q) v[q] = bf2f(xv[q]) + bf2f(pv[q]);
            } else {
                v = *(const floatx4*)(xf + rowbase + (size_t)wc * Cc);
            }
            r[dy][j] = v;
        }
    }
    // edge masks (wave-uniform, register-only)
    if (h == 0) {
        #pragma unroll
        for (int j = 0; j < 10; ++j) r[0][j] = zf;
    }
    if (h == Hh - 1) {
        #pragma unroll
        for (int j = 0; j < 10; ++j) r[2][j] = zf;
    }
    if (w0 == 0)      { r[0][0] = zf; r[1][0] = zf; r[2][0] = zf; }
    if (w0 == Wd - 8) { r[0][9] = zf; r[1][9] = zf; r[2][9] = zf; }

    // ---- stencil: 8 tokens, pure register FMAs ----
    floatx4 val[8];
    #pragma unroll
    for (int tk = 0; tk < 8; ++tk) {
        floatx4 a = bcv;
        #pragma unroll
        for (int dy = 0; dy < 3; ++dy) {
            #pragma unroll
            for (int dx = 0; dx < 3; ++dx) {
                const int t = dy * 3 + dx;
                floatx4 v = r[dy][tk + dx];
                #pragma unroll
                for (int j = 0; j < 4; ++j)
                    a[j] += wreg[j * 9 + t] * v[j];
            }
        }
        floatx4 xc = r[1][tk + 1];               // center (residual input y)
        #pragma unroll
        for (int j = 0; j < 4; ++j) val[tk][j] = xc[j] + a[j];
    }

    // ---- 8 interleaved LN reductions (lanes 48-63 contribute zero) ----
    float s[8], s2[8];
    #pragma unroll
    for (int tk = 0; tk < 8; ++tk) {
        float a = val[tk][0] + val[tk][1] + val[tk][2] + val[tk][3];
        float a2 = val[tk][0]*val[tk][0] + val[tk][1]*val[tk][1]
                 + val[tk][2]*val[tk][2] + val[tk][3]*val[tk][3];
        s[tk]  = act ? a  : 0.f;
        s2[tk] = act ? a2 : 0.f;
    }
    #pragma unroll
    for (int off = 1; off < 64; off <<= 1) {
        #pragma unroll
        for (int tk = 0; tk < 8; ++tk) {
            s[tk]  += __shfl_xor(s[tk],  off, 64);
            s2[tk] += __shfl_xor(s2[tk], off, 64);
        }
    }

    // ---- epilogue: residual bf16 store + LN bf16 store ----
    const int blk0 = (b * Hh + h) * Wd + w0;
    #pragma unroll
    for (int tk = 0; tk < 8; ++tk) {
        const float mean = s[tk] * (1.0f / Cc);
        const float var  = s2[tk] * (1.0f / Cc) - mean * mean;
        const float rs   = rsqrtf(var + 1e-5f);
        int rr;
        if (windowed) {
            int win = b * 64 + (h & 7) * 8 + tk;     // (w0+tk)&7 == tk
            int pos = (h >> 3) * 7 + wslot;          // (w0+tk)>>3 == wslot
            rr = win * 49 + pos;
        } else {
            rr = blk0 + tk;
        }
        if (act) {
            s4v ys, o;
            #pragma unroll
            for (int j = 0; j < 4; ++j) {
                ys[j] = f2bf(val[tk][j]);
                o[j]  = f2bf((val[tk][j] - mean) * rs * gv[j] + bv[j]);
            }
            *(s4v*)(ysum_out + (size_t)(blk0 + tk) * Cc + c4) = ys;
            *(s4v*)(ln_out + (size_t)rr * Cc + c4) = o;
        }
    }
}

// ---------------------------------------------------------------------------
// Tiled MFMA GEMM: BM=128, BN=64, BK=32, 256 thr / 4 waves.
// Double-buffered 2-phase pipeline; one barrier per K-iter.
// EPI==0: qkv output (bf16, permuted-column bias remap)
// EPI==2: fc1 + exact GELU, bf16 stride HIDN
// EPI==3: fc2, PURE WRITE out = bf2f(aux[ybuf]) + v (no RMW)
// EPI==4: proj, dense bf16 write in window-row order (residual added later)
// ---------------------------------------------------------------------------
template<int K, int EPI>
__global__ void __launch_bounds__(256) k_gemm_tiled(
    const short* __restrict__ A, const short* __restrict__ BT,
    const float* __restrict__ bias, void* __restrict__ outp,
    const short* __restrict__ aux)
{
    __shared__ __align__(16) short As[2][128 * 32];
    __shared__ __align__(16) short Bs[2][64 * 32];
    const int tid = threadIdx.x;
    const int gx = gridDim.x;
    const int flat = blockIdx.y * gx + blockIdx.x;
    const int swz = xcd_swz(flat, gx * gridDim.y);
    const int n0 = (swz % gx) * 64;
    const int m0 = (swz / gx) * 128;
    const int w = tid >> 6, lane = tid & 63;
    const int lcol = lane & 15, quad = lane >> 4;

    floatx4 acc[2][4];
    #pragma unroll
    for (int mi = 0; mi < 2; ++mi)
        #pragma unroll
        for (int ni = 0; ni < 4; ++ni) acc[mi][ni] = (floatx4){0, 0, 0, 0};

    const int ar = tid >> 2, ac = (tid & 3) * 8;
    const short* agp  = A + (size_t)(m0 + ar) * K + ac;
    const short* agp2 = A + (size_t)(m0 + 64 + ar) * K + ac;
    const short* bgp  = BT + (size_t)(n0 + ar) * K + ac;

    const int aoff = w * 32 + lcol;      // fragment row for this lane

    // prologue: stage tile 0 into buffer 0
    gl_lds16(agp, &As[0][tid * 8]);
    gl_lds16(agp2, &As[0][64 * 32 + tid * 8]);
    gl_lds16(bgp, &Bs[0][tid * 8]);

    #pragma unroll 2
    for (int t = 0; t < K / 32; ++t) {
        const int b = t & 1;
        __syncthreads();                 // drains DMA for buf b; prior reads done
        if (t + 1 < K / 32) {            // issue next tile into other buffer
            const int k1 = (t + 1) * 32;
            gl_lds16(agp + k1, &As[b ^ 1][tid * 8]);
            gl_lds16(agp2 + k1, &As[b ^ 1][64 * 32 + tid * 8]);
            gl_lds16(bgp + k1, &Bs[b ^ 1][tid * 8]);
        }
        short8 a0 = *(const short8*)&As[b][aoff * 32 + quad * 8];
        short8 a1 = *(const short8*)&As[b][(aoff + 16) * 32 + quad * 8];
        #pragma unroll
        for (int ni = 0; ni < 4; ++ni) {
            short8 bb = *(const short8*)&Bs[b][(ni * 16 + lcol) * 32 + quad * 8];
            acc[0][ni] = __builtin_amdgcn_mfma_f32_16x16x32_bf16(a0, bb, acc[0][ni], 0, 0, 0);
            acc[1][ni] = __builtin_amdgcn_mfma_f32_16x16x32_bf16(a1, bb, acc[1][ni], 0, 0, 0);
        }
    }

    #pragma unroll
    for (int mi = 0; mi < 2; ++mi) {
        #pragma unroll
        for (int ni = 0; ni < 4; ++ni) {
            int col = n0 + ni * 16 + lcol;
            float bv;
            if (EPI == 0) {
                // permuted-column layout: col = k*192 + h*32 + d
                int d = col & 31, hh = (col >> 5) % 6, k3 = col / 192;
                bv = bias[d * 18 + k3 * 6 + hh];
            } else {
                bv = bias[col];
            }
            #pragma unroll
            for (int t = 0; t < 4; ++t) {
                int row = m0 + w * 32 + mi * 16 + quad * 4 + t;
                float v = acc[mi][ni][t] + bv;
                if (EPI == 0) {
                    ((short*)outp)[(size_t)row * 576 + col] = f2bf(v);
                } else if (EPI == 2) {
                    float gl = 0.5f * v * (1.0f + erff(v * 0.70710678118654752f));
                    ((short*)outp)[(size_t)row * HIDN + col] = f2bf(gl);
                } else if (EPI == 3) {
                    ((float*)outp)[(size_t)row * Cc + col] =
                        bf2f(aux[(size_t)row * Cc + col]) + v;
                } else {
                    ((short*)outp)[(size_t)row * Cc + col] = f2bf(v);
                }
            }
        }
    }
}

// ---------------------------------------------------------------------------
// MFMA window attention: one wave (64 thr) per (window, head).
// qkvbuf column layout is [k*192 + h*32 + d] -> Q/K/V rows for a given
// (k,h) are 32 consecutive shorts (64B, 64B-aligned). Staging loads are
// short8, fully coalesced. LDS overlay: P reuses dead Q/K region.
// ---------------------------------------------------------------------------
__global__ void __launch_bounds__(64) k_attn(
    const short* __restrict__ C, short* __restrict__ aout)
{
    int h = blockIdx.x, win = blockIdx.y;
    int lane = threadIdx.x;
    int lcol = lane & 15, quad = lane >> 4;
    __shared__ __align__(16) short buf[7424];
    short* Q  = buf;            // [64*40]
    short* Kb = buf + 2560;     // [64*40]
    short* Vt = buf + 5120;     // [32*72]
    short* P  = buf;            // [64*72] overlays Q+Kb after S-phase

    const short8 z8 = {0, 0, 0, 0, 0, 0, 0, 0};
    const size_t wbase = (size_t)win * 49 * 576;
    const int hq = h * 32;
    const int pr = lane >> 2, d8 = (lane & 3) * 8;

    // Q and K: 16 rows per wave-iteration, 64B contiguous per row
    #pragma unroll
    for (int it = 0; it < 4; ++it) {
        int pp = pr + it * 16;
        bool ok = pp < 49;
        size_t ro = wbase + (size_t)(ok ? pp : 0) * 576 + hq + d8;
        short8 vq = ok ? *(const short8*)(C + ro)       : z8;
        short8 vk = ok ? *(const short8*)(C + ro + 192) : z8;
        *(short8*)(Q  + pp * 40 + d8) = vq;
        *(short8*)(Kb + pp * 40 + d8) = vk;
    }
    // V: coalesced row loads, transposed scatter into Vt[d][p]
    #pragma unroll
    for (int it = 0; it < 4; ++it) {
        int pp = pr + it * 16;
        bool ok = pp < 49;
        size_t ro = wbase + (size_t)(ok ? pp : 0) * 576 + 384 + hq + d8;
        short8 vv = ok ? *(const short8*)(C + ro) : z8;
        #pragma unroll
        for (int j = 0; j < 8; ++j)
            Vt[(d8 + j) * 72 + pp] = vv[j];
    }

    floatx4 s[4][4];
    #pragma unroll
    for (int mi = 0; mi < 4; ++mi) {
        short8 aq = *(const short8*)(Q + (mi * 16 + lcol) * 40 + quad * 8);
        #pragma unroll
        for (int ni = 0; ni < 4; ++ni) {
            short8 bk = *(const short8*)(Kb + (ni * 16 + lcol) * 40 + quad * 8);
            floatx4 z = {0, 0, 0, 0};
            s[mi][ni] = __builtin_amdgcn_mfma_f32_16x16x32_bf16(aq, bk, z, 0, 0, 0);
        }
    }

    const float scale = 0.17677669529663688f;   // 1/sqrt(32)
    #pragma unroll
    for (int mi = 0; mi < 4; ++mi) {
        #pragma unroll
        for (int reg = 0; reg < 4; ++reg) {
            float vv[4];
            float mx = -3e38f;
            #pragma unroll
            for (int ni = 0; ni < 4; ++ni) {
                int col = ni * 16 + lcol;
                float v = (col < 49) ? s[mi][ni][reg] * scale : -3e38f;
                vv[ni] = v;
                mx = fmaxf(mx, v);
            }
            #pragma unroll
            for (int off = 1; off < 16; off <<= 1)
                mx = fmaxf(mx, __shfl_xor(mx, off, 64));
            float sum = 0.f;
            #pragma unroll
            for (int ni = 0; ni < 4; ++ni) {
                int col = ni * 16 + lcol;
                float e = (col < 49) ? __expf(vv[ni] - mx) : 0.f;
                vv[ni] = e;
                sum += e;
            }
            #pragma unroll
            for (int off = 1; off < 16; off <<= 1)
                sum += __shfl_xor(sum, off, 64);
            float inv = 1.0f / sum;
            int row = mi * 16 + quad * 4 + reg;
            #pragma unroll
            for (int ni = 0; ni < 4; ++ni)
                P[row * 72 + ni * 16 + lcol] = f2bf(vv[ni] * inv);
        }
    }

    #pragma unroll
    for (int mi = 0; mi < 4; ++mi) {
        short8 a0 = *(const short8*)(P + (mi * 16 + lcol) * 72 + quad * 8);
        short8 a1 = *(const short8*)(P + (mi * 16 + lcol) * 72 + 32 + quad * 8);
        #pragma unroll
        for (int nd = 0; nd < 2; ++nd) {
            short8 b0 = *(const short8*)(Vt + (nd * 16 + lcol) * 72 + quad * 8);
            short8 b1 = *(const short8*)(Vt + (nd * 16 + lcol) * 72 + 32 + quad * 8);
            floatx4 z = {0, 0, 0, 0};
            floatx4 o = __builtin_amdgcn_mfma_f32_16x16x32_bf16(a0, b0, z, 0, 0, 0);
            o = __builtin_amdgcn_mfma_f32_16x16x32_bf16(a1, b1, o, 0, 0, 0);
            #pragma unroll
            for (int reg = 0; reg < 4; ++reg) {
                int row = mi * 16 + quad * 4 + reg;
                if (row < 49)
                    aout[((size_t)win * 49 + row) * Cc + h * HDim + nd * 16 + lcol] =
                        f2bf(o[reg]);
            }
        }
    }
}

// ---------------------------------------------------------------------------
extern "C" void kernel_launch(void* const* d_in, const int* in_sizes, int n_in,
                              void* d_out, int out_size, void* d_ws, size_t ws_size,
                              hipStream_t stream)
{
    (void)in_sizes; (void)n_in; (void)out_size; (void)ws_size;
    const float* x      = (const float*)d_in[0];
    const float* cpe0_w = (const float*)d_in[3];
    const float* cpe0_b = (const float*)d_in[4];
    const float* cpe1_w = (const float*)d_in[5];
    const float* cpe1_b = (const float*)d_in[6];
    const float* n1_g   = (const float*)d_in[7];
    const float* n1_b   = (const float*)d_in[8];
    const float* qkv_w  = (const float*)d_in[9];
    const float* qkv_b  = (const float*)d_in[10];
    const float* proj_w = (const float*)d_in[11];
    const float* proj_b = (const float*)d_in[12];
    const float* n2_g   = (const float*)d_in[13];
    const float* n2_b   = (const float*)d_in[14];
    const float* fc1_w  = (const float*)d_in[15];
    const float* fc1_b  = (const float*)d_in[16];
    const float* fc2_w  = (const float*)d_in[17];
    const float* fc2_b  = (const float*)d_in[18];
    float* out = (float*)d_out;

    char* ws = (char*)d_ws;
    short* shortcut = (short*)ws;                     // 38,535,168  (bf16 Tt*192)
    short* ybuf     = (short*)(ws + 38535168);        // 38,535,168  (bf16 Tt*192)
    short* lnbuf    = (short*)(ws + 77070336);        // 38,535,168  (bf16 Tt*192)
    short* qkvbuf   = (short*)(ws + 115605504);       // 115,605,504 (bf16 Tt*576)
    short* attnout  = (short*)(ws + 231211008);       // 38,535,168
    short* projbuf  = qkvbuf;                         // overlays dead qkvbuf
    short* h1       = qkvbuf;                         // fc1 out overlays proj+attn
    short* wqkvT    = (short*)(ws + 269746176);       // 221,184
    short* wprojT   = (short*)(ws + 269967360);       // 73,728
    short* wfc1T    = (short*)(ws + 270041088);       // 294,912
    short* wfc2T    = (short*)(ws + 270336000);       // 294,912

    k_transpose_all<<<dim3((NQKV + NPRJ + NFC1 + NFC2 + 255) / 256), dim3(256), 0, stream>>>(
        qkv_w, proj_w, fc1_w, fc2_w, wqkvT, wprojT, wfc1T, wfc2T);

    k_cpe_ln<0><<<dim3(Tt / 32), dim3(256), 0, stream>>>(x, cpe0_w, cpe0_b, n1_g, n1_b,
                                                         shortcut, lnbuf, 1, nullptr);
    k_gemm_tiled<192, 0><<<dim3(9, Tt / 128), dim3(256), 0, stream>>>(lnbuf, wqkvT, qkv_b, qkvbuf, nullptr);
    k_attn<<<dim3(NHh, NWIN), dim3(64), 0, stream>>>(qkvbuf, attnout);
    // proj: dense bf16 write in window-row order (no RMW scatter)
    k_gemm_tiled<192, 4><<<dim3(3, Tt / 128), dim3(256), 0, stream>>>(attnout, wprojT, proj_b, projbuf, nullptr);
    // cpe_ln#2 fuses the residual add y = shortcut + proj; y -> bf16 ybuf
    k_cpe_ln<1><<<dim3(Tt / 32), dim3(256), 0, stream>>>(shortcut, cpe1_w, cpe1_b, n2_g, n2_b,
                                                         ybuf, lnbuf, 0, projbuf);
    k_gemm_tiled<192, 2><<<dim3(12, Tt / 128), dim3(256), 0, stream>>>(lnbuf, wfc1T, fc1_b, h1, nullptr);
    // fc2: pure write out = y + h  (no read-modify-write of out)
    k_gemm_tiled<768, 3><<<dim3(3, Tt / 128), dim3(256), 0, stream>>>(h1, wfc2T, fc2_b, out, ybuf);
}